// Round 9
// baseline (136.528 us; speedup 1.0000x reference)
//
#include <hip/hip_runtime.h>
#include <math.h>

// Problem constants (match reference)
constexpr int cB = 2, cN = 8192, cS = 4096;
constexpr int cTR = 12;    // stored trans channels (0-5 before, 6-11 after)
constexpr int CAP = 96;    // survivor slots per query (full-sample gate: ~12 expected)
constexpr int QPB = 8;     // queries per knn block
constexpr int TPB = 512;   // knn threads per block (8 waves) — keeps 8 waves/SIMD at QPB=8

typedef unsigned long long ull;

// ---- exact distance: EXACTLY mirrors reference arithmetic ----
// ref: sq = (x*x + y*y) + z*z ; d2 = (sq_i + sq_j) - 2*dot ; d = sqrt(max(d2,1e-12))
__device__ __forceinline__ float d2exact_rn(float qx, float qy, float qz, float qw,
                                            float cx, float cy, float cz, float cw) {
  float dot = __fadd_rn(__fadd_rn(__fmul_rn(qx, cx), __fmul_rn(qy, cy)), __fmul_rn(qz, cz));
  return __fsub_rn(__fadd_rn(qw, cw), __fmul_rn(2.0f, dot));
}
__device__ __forceinline__ float dist_rn4(float4 a, float4 b) {
  return sqrtf(fmaxf(d2exact_rn(a.x, a.y, a.z, a.w, b.x, b.y, b.z, b.w), 1e-12f));
}
__device__ __forceinline__ void ce64(ull& a, ull& b) {
  ull lo = a < b ? a : b;
  ull hi = a < b ? b : a;
  a = lo; b = hi;
}
__device__ __forceinline__ void cef(float& a, float& b) {
  float lo = fminf(a, b), hi = fmaxf(a, b);
  a = lo; b = hi;
}
// 6-step bitonic top-4 butterfly over 64 lanes. Input: per-lane SORTED quad a0<=a1<=a2<=a3.
// Output: all lanes hold the sorted 4 smallest of all 256 values. (Verified r2.)
__device__ __forceinline__ void top4_merge64(float& a0, float& a1, float& a2, float& a3) {
  #pragma unroll
  for (int off = 1; off < 64; off <<= 1) {
    float s0 = __shfl_xor(a0, off, 64), s1 = __shfl_xor(a1, off, 64);
    float s2 = __shfl_xor(a2, off, 64), s3 = __shfl_xor(a3, off, 64);
    float n0 = fminf(a0, s3), n1 = fminf(a1, s2), n2 = fminf(a2, s1), n3 = fminf(a3, s0);
    float t;
    t = fminf(n0, n2); n2 = fmaxf(n0, n2); n0 = t;
    t = fminf(n1, n3); n3 = fmaxf(n1, n3); n1 = t;
    t = fminf(n0, n1); n1 = fmaxf(n0, n1); n0 = t;
    t = fminf(n2, n3); n3 = fmaxf(n2, n3); n2 = t;
    a0 = n0; a1 = n1; a2 = n2; a3 = n3;
  }
}

// ---- K1: pack. P = orig order (clean sq); P2 = sampled-first permuted; idxMap -> orig ----
// smp sorted per batch: sampled rank lo via binary search; unsampled pos = cS + n - lo.
__global__ __launch_bounds__(512) void pack_kernel(const float* __restrict__ xyz,
                                                   const int* __restrict__ smp,
                                                   float4* __restrict__ P,
                                                   float4* __restrict__ P2,
                                                   int* __restrict__ idxMap,
                                                   float* __restrict__ oxyz) {
  int t = blockIdx.x * 512 + threadIdx.x;
  if (t < cB * cN) {
    int b = t >> 13, n = t & (cN - 1);
    const float* p = xyz + t * 3;
    float x = p[0], y = p[1], z = p[2];
    float sq = __fadd_rn(__fadd_rn(__fmul_rn(x, x), __fmul_rn(y, y)), __fmul_rn(z, z));
    const int* sb = smp + b * cS;
    int lo = 0, hi = cS;
    while (lo < hi) { int mid = (lo + hi) >> 1; if (sb[mid] < n) lo = mid + 1; else hi = mid; }
    bool flg = (lo < cS) && (sb[lo] == n);
    P[t] = make_float4(x, y, z, sq);
    int pos = flg ? lo : (cS + n - lo);
    int gp = b * cN + pos;
    P2[gp] = make_float4(x, y, z, sq);
    idxMap[gp] = n;
  } else if (t < cB * cN + cB * cS) {
    int j = t - cB * cN;
    int b = j >> 12;
    const float* p = xyz + (b * cN + smp[j]) * 3;
    oxyz[j * 3 + 0] = p[0]; oxyz[j * 3 + 1] = p[1]; oxyz[j * 3 + 2] = p[2];
  }
}

// ---- K2: 4-NN both modes. r7-verified config (equal-best): QPB=8, 512-thr blocks,
// 1024 blocks = 8 waves/SIMD, full-sample gate, folded f' domain, LDS-transpose tau,
// exact re-score + u64 butterfly (bit-identical to reference top_k). UNCHANGED.
#define KNN_FORQ(M) M(0) M(1) M(2) M(3) M(4) M(5) M(6) M(7)

__global__ __launch_bounds__(512, 8) void knn_kernel(const float4* __restrict__ P2,
                                                     const int* __restrict__ idxMap,
                                                     float* __restrict__ trans,
                                                     int* __restrict__ AB,
                                                     int* __restrict__ AA) {
  __shared__ int sPos[QPB][CAP];
  __shared__ int sCnt[QPB];
  __shared__ alignas(16) float tmpAll[QPB][TPB];   // [query][tid] lane minima (16 KB)
  __shared__ alignas(16) float gBuf[QPB];

  const int tid = threadIdx.x, wv = tid >> 6, lane = tid & 63;
  const int qbase = blockIdx.x * QPB;      // 8 | 4096 -> same batch
  const int b = qbase >> 12;
  const int s0 = qbase & (cS - 1);
  const float4* Cb = P2 + b * cN;
  const int* im = idxMap + b * cN;
  const float INF = __uint_as_float(0x7f800000u);
  const float MARGIN = 2e-3f;

  // fast coeffs (-2x,-2y,-2z) per query; q.w folded out of the scan (constant shift)
#define KNN_LOADQ(i) \
  const float4 q##i = Cb[s0 + i]; \
  const float qx##i = -2.0f * q##i.x, qy##i = -2.0f * q##i.y, qz##i = -2.0f * q##i.z;
  KNN_FORQ(KNN_LOADQ)
#undef KNN_LOADQ
  if (tid < QPB) sCnt[tid] = 0;

  // ---- Pass A: full sampled region [0, cS), per-lane fast minima (f' domain) ----
  float mn0 = INF, mn1 = INF, mn2 = INF, mn3 = INF;
  float mn4 = INF, mn5 = INF, mn6 = INF, mn7 = INF;
  #pragma unroll 4
  for (int k = 0; k < 8; k++) {
    float4 cp = Cb[k * TPB + tid];
#define KNN_AMIN(i) mn##i = fminf(mn##i, fmaf(qz##i, cp.z, fmaf(qy##i, cp.y, fmaf(qx##i, cp.x, cp.w))));
    KNN_FORQ(KNN_AMIN)
#undef KNN_AMIN
  }
#define KNN_WMIN(i) tmpAll[i][tid] = mn##i;
  KNN_FORQ(KNN_WMIN)
#undef KNN_WMIN
  __syncthreads();                          // publishes tmpAll + sCnt = 0

  // ---- tau: wave wv reduces query wv — exact 4th-smallest of its 512 lane-minima ----
  {
    // stride-64 reads: consecutive lanes -> consecutive addresses, conflict-free
    float v0 = tmpAll[wv][lane +   0], v1 = tmpAll[wv][lane +  64];
    float v2 = tmpAll[wv][lane + 128], v3 = tmpAll[wv][lane + 192];
    float v4 = tmpAll[wv][lane + 256], v5 = tmpAll[wv][lane + 320];
    float v6 = tmpAll[wv][lane + 384], v7 = tmpAll[wv][lane + 448];
    // sort quads asc
    cef(v0, v1); cef(v2, v3); cef(v0, v2); cef(v1, v3); cef(v1, v2);
    cef(v4, v5); cef(v6, v7); cef(v4, v6); cef(v5, v7); cef(v5, v6);
    // bitonic merge, keep 4 smallest sorted
    float a0 = fminf(v0, v7), a1 = fminf(v1, v6), a2 = fminf(v2, v5), a3 = fminf(v3, v4);
    cef(a0, a2); cef(a1, a3); cef(a0, a1); cef(a2, a3);
    top4_merge64(a0, a1, a2, a3);
    if (lane == 0) gBuf[wv] = a3 + MARGIN;
  }
  __syncthreads();
  const float g0 = gBuf[0], g1 = gBuf[1], g2 = gBuf[2], g3 = gBuf[3];
  const float g4 = gBuf[4], g5 = gBuf[5], g6 = gBuf[6], g7 = gBuf[7];

  // ---- Pass B: full scan, fast gate; outer hit-guard + tiny position-push interior ----
  #pragma unroll 2
  for (int k = 0; k < 16; k++) {
    int j = k * TPB + tid;
    float4 cp = Cb[j];
#define KNN_F(i) float f##i = fmaf(qz##i, cp.z, fmaf(qy##i, cp.y, fmaf(qx##i, cp.x, cp.w)));
    KNN_FORQ(KNN_F)
#undef KNN_F
    bool hit = (f0 <= g0) | (f1 <= g1) | (f2 <= g2) | (f3 <= g3)
             | (f4 <= g4) | (f5 <= g5) | (f6 <= g6) | (f7 <= g7);
    if (hit) {                             // rare: skipped wholesale when no lane hits
#define KNN_PUSH(i) if (f##i <= g##i) { int s = atomicAdd(&sCnt[i], 1); if (s < CAP) sPos[i][s] = j; }
      KNN_FORQ(KNN_PUSH)
#undef KNN_PUSH
    }
  }
  __syncthreads();

  // ---- final: exact keys for survivors, u64 butterfly per (query, mode); wave wv owns
  // query wv x 2 modes = 2 butterflies/wave. Phase unchanged (verified).
  const ull KE = 0x7F800000FFFFFFFFull;
  const int qloc = wv;
  const float4 qv = Cb[s0 + qloc];          // exact coords, L2-hot re-read
  #pragma unroll
  for (int mode = 0; mode < 2; mode++) {
    int cnt = sCnt[qloc]; cnt = cnt > CAP ? CAP : cnt;
    ull k0 = KE, k1 = KE;
    if (lane < cnt) {
      int pos = sPos[qloc][lane];
      if (mode == 0 || pos < cS) {
        float4 cp = Cb[pos];
        float fe = fmaxf(d2exact_rn(qv.x, qv.y, qv.z, qv.w, cp.x, cp.y, cp.z, cp.w), 1e-12f);
        unsigned idx = mode ? (unsigned)pos : (unsigned)im[pos];
        k0 = ((ull)__float_as_uint(fe) << 32) | idx;
      }
    }
    if (lane + 64 < cnt) {
      int pos = sPos[qloc][lane + 64];
      if (mode == 0 || pos < cS) {
        float4 cp = Cb[pos];
        float fe = fmaxf(d2exact_rn(qv.x, qv.y, qv.z, qv.w, cp.x, cp.y, cp.z, cp.w), 1e-12f);
        unsigned idx = mode ? (unsigned)pos : (unsigned)im[pos];
        k1 = ((ull)__float_as_uint(fe) << 32) | idx;
      }
    }
    if (k1 < k0) { ull t = k0; k0 = k1; k1 = t; }
    ull k2 = KE, k3 = KE;
    #pragma unroll
    for (int off = 1; off < 64; off <<= 1) {
      ull b0 = __shfl_xor(k0, off, 64), b1 = __shfl_xor(k1, off, 64);
      ull b2 = __shfl_xor(k2, off, 64), b3 = __shfl_xor(k3, off, 64);
      ull m0 = k0 < b3 ? k0 : b3;
      ull m1 = k1 < b2 ? k1 : b2;
      ull m2 = k2 < b1 ? k2 : b1;
      ull m3 = k3 < b0 ? k3 : b0;
      ce64(m0, m2); ce64(m1, m3); ce64(m0, m1); ce64(m2, m3);
      k0 = m0; k1 = m1; k2 = m2; k3 = m3;
    }
    if (lane == 0) {
      int wq = qbase + qloc;
      int i0 = (int)(unsigned)k0, i1 = (int)(unsigned)k1;
      int i2 = (int)(unsigned)k2, i3 = (int)(unsigned)k3;
      float e1 = sqrtf(__uint_as_float((unsigned)(k1 >> 32)));
      float e2 = sqrtf(__uint_as_float((unsigned)(k2 >> 32)));
      float e3 = sqrtf(__uint_as_float((unsigned)(k3 >> 32)));
      float* tr = trans + wq * cTR + (mode ? 6 : 0);
      tr[0] = e1; tr[1] = e2; tr[2] = e3;
      int* ao = (mode ? AA : AB) + wq * 4;
      if (mode) { i0 = im[i0]; i1 = im[i1]; i2 = im[i2]; i3 = im[i3]; }
      ao[0] = i0; ao[1] = i1; ao[2] = i2; ao[3] = i3;
    }
  }
}

// ---- K3: anchor-anchor dists + 3-layer MLP. r9: split-K across 4 waves.
// r4/r8 causal chain: mlp time scales with waves/SIMD (1->2->4 waves/SIMD: ~21->~15->~12.5us)
// — weight-load-latency-bound. This round: 256-thr blocks (4 waves), grid 2048 ->
// 8 blocks/CU x 4 waves = 32 waves/CU = 8 waves/SIMD (2x round 8). Per-wave k-ranges:
// L1 7, L2 16, L3 32 iters; per-block weight traffic unchanged. Combine via part[4][8][64]
// (8 KB, lane-stride-1 conflict-free): wave w owns row w (all 4 waves busy; L3 both
// channel halves). LDS ~12.5 KB/block x 8 blocks = 100 KB/CU OK. Numerics: 4-term split
// sum, same O(1e-4) class as the r8-verified 2-way split.
__global__ __launch_bounds__(256, 4) void mlp_kernel(
    const float* __restrict__ TR, const float4* __restrict__ P,
    const int* __restrict__ AB, const int* __restrict__ AA,
    const float* __restrict__ feat, const int* __restrict__ smp,
    const float* __restrict__ w1, const float* __restrict__ b1,
    const float* __restrict__ g1, const float* __restrict__ be1,
    const float* __restrict__ w2, const float* __restrict__ b2,
    const float* __restrict__ g2, const float* __restrict__ be2,
    const float* __restrict__ w3, const float* __restrict__ b3,
    const float* __restrict__ g3, const float* __restrict__ be3,
    float* __restrict__ out) {
  __shared__ alignas(16) float tinT[28 * 4];
  __shared__ alignas(16) float act1T[64 * 4];
  __shared__ alignas(16) float act2T[128 * 4];   // ch 0..63 = feat, 64..127 = L2 out
  __shared__ alignas(16) float part[4][8][64];   // [wave][acc-slot][lane] partials (8 KB)

  const int tid = threadIdx.x;
  const int lane = tid & 63, w = tid >> 6;
  const int r0 = blockIdx.x * 4;
  const int b = r0 >> 12;
  const float inv = 1.0f / sqrtf(1.0f + 1e-5f);

  float pb1 = b1[lane], pg1 = g1[lane] * inv, pe1 = be1[lane];
  float pb2 = b2[lane], pg2 = g2[lane] * inv, pe2 = be2[lane];
  float pb3a = b3[lane],      pg3a = g3[lane] * inv,      pe3a = be3[lane];
  float pb3b = b3[lane + 64], pg3b = g3[lane + 64] * inv, pe3b = be3[lane + 64];

  // stage feat -> act2T ch 0..63: thread handles ch=lane, row=w (256 thr = 64ch x 4r)
  {
    const float* fb = feat + (size_t)b * cN * 64;
    act2T[lane * 4 + w] = fb[smp[r0 + w] * 64 + lane];
  }
  // stage tinT (28ch x 4r = 112 items): 256 threads, single pass
  {
    const float4* Pb = P + b * cN;
    int idx = tid;
    if (idx < 112) {
      int r = idx & 3, ch = idx >> 2;
      float v;
      if (ch < 3) {
        v = TR[(r0 + r) * cTR + ch];
      } else if (ch < 6) {
        int pi = (ch == 3) ? 1 : 1 + (ch - 4), pj = (ch == 3) ? 2 : 3;
        if (ch == 5) { pi = 2; pj = 3; }
        v = dist_rn4(Pb[AB[(r0 + r) * 4 + pi]], Pb[AB[(r0 + r) * 4 + pj]]);
      } else if (ch < 9) {
        v = TR[(r0 + r) * cTR + ch];
      } else if (ch < 12) {
        int cc = ch - 9;
        int pi = (cc == 0) ? 1 : ((cc == 1) ? 1 : 2);
        int pj = (cc == 0) ? 2 : 3;
        v = dist_rn4(Pb[AA[(r0 + r) * 4 + pi]], Pb[AA[(r0 + r) * 4 + pj]]);
      } else {
        int cc = ch - 12;
        int gi = AB[(r0 + r) * 4 + (cc >> 2)];
        int gj = AA[(r0 + r) * 4 + (cc & 3)];
        v = dist_rn4(Pb[gi], Pb[gj]);
      }
      tinT[ch * 4 + r] = v;
    }
  }
  __syncthreads();

  // L1: 28 -> 64, k-split: wave w does [7w, 7w+7)
  {
    float4 acc = (w == 0) ? make_float4(pb1, pb1, pb1, pb1)
                          : make_float4(0.f, 0.f, 0.f, 0.f);
    #pragma unroll 7
    for (int k = 7 * w; k < 7 * w + 7; k++) {
      float ww = w1[k * 64 + lane];
      float4 a = *(const float4*)&tinT[k * 4];
      acc.x = fmaf(a.x, ww, acc.x); acc.y = fmaf(a.y, ww, acc.y);
      acc.z = fmaf(a.z, ww, acc.z); acc.w = fmaf(a.w, ww, acc.w);
    }
    part[w][0][lane] = acc.x; part[w][1][lane] = acc.y;
    part[w][2][lane] = acc.z; part[w][3][lane] = acc.w;
    __syncthreads();
    // combine: wave w handles row w
    float o = ((part[0][w][lane] + part[1][w][lane])
             + (part[2][w][lane] + part[3][w][lane]));
    o = fmaf(o, pg1, pe1);
    o = o >= 0.0f ? o : 0.2f * o;
    __syncthreads();                      // part reuse guard
    act1T[lane * 4 + w] = o;
  }
  __syncthreads();
  // L2: 64 -> 64, k-split: wave w does [16w, 16w+16)
  {
    float4 acc = (w == 0) ? make_float4(pb2, pb2, pb2, pb2)
                          : make_float4(0.f, 0.f, 0.f, 0.f);
    #pragma unroll 8
    for (int k = 16 * w; k < 16 * w + 16; k++) {
      float ww = w2[k * 64 + lane];
      float4 a = *(const float4*)&act1T[k * 4];
      acc.x = fmaf(a.x, ww, acc.x); acc.y = fmaf(a.y, ww, acc.y);
      acc.z = fmaf(a.z, ww, acc.z); acc.w = fmaf(a.w, ww, acc.w);
    }
    part[w][0][lane] = acc.x; part[w][1][lane] = acc.y;
    part[w][2][lane] = acc.z; part[w][3][lane] = acc.w;
    __syncthreads();
    float o = ((part[0][w][lane] + part[1][w][lane])
             + (part[2][w][lane] + part[3][w][lane]));
    o = fmaf(o, pg2, pe2);
    o = o >= 0.0f ? o : 0.2f * o;
    __syncthreads();                      // part reuse guard
    act2T[(64 + lane) * 4 + w] = o;
  }
  __syncthreads();
  // L3: 128 -> 128 (lane covers ch and ch+64), k-split: wave w does [32w, 32w+32)
  {
    float4 aA = (w == 0) ? make_float4(pb3a, pb3a, pb3a, pb3a)
                         : make_float4(0.f, 0.f, 0.f, 0.f);
    float4 aB = (w == 0) ? make_float4(pb3b, pb3b, pb3b, pb3b)
                         : make_float4(0.f, 0.f, 0.f, 0.f);
    #pragma unroll 8
    for (int k = 32 * w; k < 32 * w + 32; k++) {
      float wA = w3[k * 128 + lane];
      float wB = w3[k * 128 + 64 + lane];
      float4 a = *(const float4*)&act2T[k * 4];
      aA.x = fmaf(a.x, wA, aA.x); aA.y = fmaf(a.y, wA, aA.y);
      aA.z = fmaf(a.z, wA, aA.z); aA.w = fmaf(a.w, wA, aA.w);
      aB.x = fmaf(a.x, wB, aB.x); aB.y = fmaf(a.y, wB, aB.y);
      aB.z = fmaf(a.z, wB, aB.z); aB.w = fmaf(a.w, wB, aB.w);
    }
    part[w][0][lane] = aA.x; part[w][1][lane] = aA.y;
    part[w][2][lane] = aA.z; part[w][3][lane] = aA.w;
    part[w][4][lane] = aB.x; part[w][5][lane] = aB.y;
    part[w][6][lane] = aB.z; part[w][7][lane] = aB.w;
    __syncthreads();
    // combine + store: wave w handles row w, both channel halves
    float sA = ((part[0][w][lane]     + part[1][w][lane])
              + (part[2][w][lane]     + part[3][w][lane]));
    float sB = ((part[0][4 + w][lane] + part[1][4 + w][lane])
              + (part[2][4 + w][lane] + part[3][4 + w][lane]));
    float xA = fmaf(sA, pg3a, pe3a);
    float xB = fmaf(sB, pg3b, pe3b);
    xA = xA >= 0.0f ? xA : 0.2f * xA; xB = xB >= 0.0f ? xB : 0.2f * xB;
    out[(r0 + w) * 128 + lane] = xA; out[(r0 + w) * 128 + 64 + lane] = xB;
  }
}

extern "C" void kernel_launch(void* const* d_in, const int* in_sizes, int n_in,
                              void* d_out, int out_size, void* d_ws, size_t ws_size,
                              hipStream_t stream) {
  const float* xyz  = (const float*)d_in[0];
  const float* feat = (const float*)d_in[1];
  const int*   smp  = (const int*)d_in[2];
  const float* w1   = (const float*)d_in[3];
  const float* b1   = (const float*)d_in[4];
  const float* g1   = (const float*)d_in[5];
  const float* be1  = (const float*)d_in[6];
  const float* w2   = (const float*)d_in[7];
  const float* b2   = (const float*)d_in[8];
  const float* g2   = (const float*)d_in[9];
  const float* be2  = (const float*)d_in[10];
  const float* w3   = (const float*)d_in[11];
  const float* b3   = (const float*)d_in[12];
  const float* g3   = (const float*)d_in[13];
  const float* be3  = (const float*)d_in[14];
  float* out = (float*)d_out;

  char* ws = (char*)d_ws;
  float4* P      = (float4*)(ws);                 // 262144 B
  float4* P2     = (float4*)(ws + 262144);        // 262144 B
  int*    idxMap = (int*)(ws + 524288);           // 65536 B
  float*  TR     = (float*)(ws + 589824);         // B*S*12*4 = 393216 B
  int*    AB     = (int*)(ws + 983040);           // 131072 B
  int*    AA     = (int*)(ws + 1114112);          // 131072 B

  pack_kernel<<<48, 512, 0, stream>>>(xyz, smp, P, P2, idxMap, out);
  knn_kernel<<<cB * cS / QPB, TPB, 0, stream>>>(P2, idxMap, TR, AB, AA);
  mlp_kernel<<<2048, 256, 0, stream>>>(TR, P, AB, AA, feat, smp,
                                       w1, b1, g1, be1, w2, b2, g2, be2,
                                       w3, b3, g3, be3, out + cB * cS * 3);
}

// Round 10
// 131.410 us; speedup vs baseline: 1.0389x; 1.0389x over previous
//
#include <hip/hip_runtime.h>
#include <math.h>

// Problem constants (match reference)
constexpr int cB = 2, cN = 8192, cS = 4096;
constexpr int cTR = 12;    // stored trans channels (0-5 before, 6-11 after)
constexpr int CAP = 96;    // survivor slots per query (full-sample gate: ~12 expected)
constexpr int QPB = 8;     // queries per knn block
constexpr int TPB = 512;   // knn threads per block (8 waves) — keeps 8 waves/SIMD at QPB=8

typedef unsigned long long ull;

// ---- exact distance: EXACTLY mirrors reference arithmetic ----
// ref: sq = (x*x + y*y) + z*z ; d2 = (sq_i + sq_j) - 2*dot ; d = sqrt(max(d2,1e-12))
__device__ __forceinline__ float d2exact_rn(float qx, float qy, float qz, float qw,
                                            float cx, float cy, float cz, float cw) {
  float dot = __fadd_rn(__fadd_rn(__fmul_rn(qx, cx), __fmul_rn(qy, cy)), __fmul_rn(qz, cz));
  return __fsub_rn(__fadd_rn(qw, cw), __fmul_rn(2.0f, dot));
}
__device__ __forceinline__ float dist_rn4(float4 a, float4 b) {
  return sqrtf(fmaxf(d2exact_rn(a.x, a.y, a.z, a.w, b.x, b.y, b.z, b.w), 1e-12f));
}
__device__ __forceinline__ void ce64(ull& a, ull& b) {
  ull lo = a < b ? a : b;
  ull hi = a < b ? b : a;
  a = lo; b = hi;
}
__device__ __forceinline__ void cef(float& a, float& b) {
  float lo = fminf(a, b), hi = fmaxf(a, b);
  a = lo; b = hi;
}
// 6-step bitonic top-4 butterfly over 64 lanes. Input: per-lane SORTED quad a0<=a1<=a2<=a3.
// Output: all lanes hold the sorted 4 smallest of all 256 values. (Verified r2.)
__device__ __forceinline__ void top4_merge64(float& a0, float& a1, float& a2, float& a3) {
  #pragma unroll
  for (int off = 1; off < 64; off <<= 1) {
    float s0 = __shfl_xor(a0, off, 64), s1 = __shfl_xor(a1, off, 64);
    float s2 = __shfl_xor(a2, off, 64), s3 = __shfl_xor(a3, off, 64);
    float n0 = fminf(a0, s3), n1 = fminf(a1, s2), n2 = fminf(a2, s1), n3 = fminf(a3, s0);
    float t;
    t = fminf(n0, n2); n2 = fmaxf(n0, n2); n0 = t;
    t = fminf(n1, n3); n3 = fmaxf(n1, n3); n1 = t;
    t = fminf(n0, n1); n1 = fmaxf(n0, n1); n0 = t;
    t = fminf(n2, n3); n3 = fmaxf(n2, n3); n2 = t;
    a0 = n0; a1 = n1; a2 = n2; a3 = n3;
  }
}

// ---- K1: pack. P = orig order (clean sq); P2 = sampled-first permuted; idxMap -> orig ----
// smp sorted per batch: sampled rank lo via binary search; unsampled pos = cS + n - lo.
__global__ __launch_bounds__(512) void pack_kernel(const float* __restrict__ xyz,
                                                   const int* __restrict__ smp,
                                                   float4* __restrict__ P,
                                                   float4* __restrict__ P2,
                                                   int* __restrict__ idxMap,
                                                   float* __restrict__ oxyz) {
  int t = blockIdx.x * 512 + threadIdx.x;
  if (t < cB * cN) {
    int b = t >> 13, n = t & (cN - 1);
    const float* p = xyz + t * 3;
    float x = p[0], y = p[1], z = p[2];
    float sq = __fadd_rn(__fadd_rn(__fmul_rn(x, x), __fmul_rn(y, y)), __fmul_rn(z, z));
    const int* sb = smp + b * cS;
    int lo = 0, hi = cS;
    while (lo < hi) { int mid = (lo + hi) >> 1; if (sb[mid] < n) lo = mid + 1; else hi = mid; }
    bool flg = (lo < cS) && (sb[lo] == n);
    P[t] = make_float4(x, y, z, sq);
    int pos = flg ? lo : (cS + n - lo);
    int gp = b * cN + pos;
    P2[gp] = make_float4(x, y, z, sq);
    idxMap[gp] = n;
  } else if (t < cB * cN + cB * cS) {
    int j = t - cB * cN;
    int b = j >> 12;
    const float* p = xyz + (b * cN + smp[j]) * 3;
    oxyz[j * 3 + 0] = p[0]; oxyz[j * 3 + 1] = p[1]; oxyz[j * 3 + 2] = p[2];
  }
}

// ---- K2: 4-NN both modes. r7-verified structure: QPB=8, 512-thr blocks, 1024 blocks =
// 8 waves/SIMD, full-sample gate, folded f' domain, LDS-transpose tau, exact re-score +
// u64 butterfly (bit-identical to reference top_k). r10 change: Pass B unroll 2 -> 4 —
// 4 independent candidate loads in flight per wave to cover ~200cy L2 latency (VALU-issue
// accounting says ~9us of work vs ~33us measured: latency residual is the target).
// Spill tripwire: WRITE_SIZE (clean=640KB); launch_bounds(512,8) caps VGPR at 64.
#define KNN_FORQ(M) M(0) M(1) M(2) M(3) M(4) M(5) M(6) M(7)

__global__ __launch_bounds__(512, 8) void knn_kernel(const float4* __restrict__ P2,
                                                     const int* __restrict__ idxMap,
                                                     float* __restrict__ trans,
                                                     int* __restrict__ AB,
                                                     int* __restrict__ AA) {
  __shared__ int sPos[QPB][CAP];
  __shared__ int sCnt[QPB];
  __shared__ alignas(16) float tmpAll[QPB][TPB];   // [query][tid] lane minima (16 KB)
  __shared__ alignas(16) float gBuf[QPB];

  const int tid = threadIdx.x, wv = tid >> 6, lane = tid & 63;
  const int qbase = blockIdx.x * QPB;      // 8 | 4096 -> same batch
  const int b = qbase >> 12;
  const int s0 = qbase & (cS - 1);
  const float4* Cb = P2 + b * cN;
  const int* im = idxMap + b * cN;
  const float INF = __uint_as_float(0x7f800000u);
  const float MARGIN = 2e-3f;

  // fast coeffs (-2x,-2y,-2z) per query; q.w folded out of the scan (constant shift)
#define KNN_LOADQ(i) \
  const float4 q##i = Cb[s0 + i]; \
  const float qx##i = -2.0f * q##i.x, qy##i = -2.0f * q##i.y, qz##i = -2.0f * q##i.z;
  KNN_FORQ(KNN_LOADQ)
#undef KNN_LOADQ
  if (tid < QPB) sCnt[tid] = 0;

  // ---- Pass A: full sampled region [0, cS), per-lane fast minima (f' domain) ----
  float mn0 = INF, mn1 = INF, mn2 = INF, mn3 = INF;
  float mn4 = INF, mn5 = INF, mn6 = INF, mn7 = INF;
  #pragma unroll 4
  for (int k = 0; k < 8; k++) {
    float4 cp = Cb[k * TPB + tid];
#define KNN_AMIN(i) mn##i = fminf(mn##i, fmaf(qz##i, cp.z, fmaf(qy##i, cp.y, fmaf(qx##i, cp.x, cp.w))));
    KNN_FORQ(KNN_AMIN)
#undef KNN_AMIN
  }
#define KNN_WMIN(i) tmpAll[i][tid] = mn##i;
  KNN_FORQ(KNN_WMIN)
#undef KNN_WMIN
  __syncthreads();                          // publishes tmpAll + sCnt = 0

  // ---- tau: wave wv reduces query wv — exact 4th-smallest of its 512 lane-minima ----
  {
    // stride-64 reads: consecutive lanes -> consecutive addresses, conflict-free
    float v0 = tmpAll[wv][lane +   0], v1 = tmpAll[wv][lane +  64];
    float v2 = tmpAll[wv][lane + 128], v3 = tmpAll[wv][lane + 192];
    float v4 = tmpAll[wv][lane + 256], v5 = tmpAll[wv][lane + 320];
    float v6 = tmpAll[wv][lane + 384], v7 = tmpAll[wv][lane + 448];
    // sort quads asc
    cef(v0, v1); cef(v2, v3); cef(v0, v2); cef(v1, v3); cef(v1, v2);
    cef(v4, v5); cef(v6, v7); cef(v4, v6); cef(v5, v7); cef(v5, v6);
    // bitonic merge, keep 4 smallest sorted
    float a0 = fminf(v0, v7), a1 = fminf(v1, v6), a2 = fminf(v2, v5), a3 = fminf(v3, v4);
    cef(a0, a2); cef(a1, a3); cef(a0, a1); cef(a2, a3);
    top4_merge64(a0, a1, a2, a3);
    if (lane == 0) gBuf[wv] = a3 + MARGIN;
  }
  __syncthreads();
  const float g0 = gBuf[0], g1 = gBuf[1], g2 = gBuf[2], g3 = gBuf[3];
  const float g4 = gBuf[4], g5 = gBuf[5], g6 = gBuf[6], g7 = gBuf[7];

  // ---- Pass B: full scan, fast gate; outer hit-guard + tiny position-push interior ----
  #pragma unroll 4
  for (int k = 0; k < 16; k++) {
    int j = k * TPB + tid;
    float4 cp = Cb[j];
#define KNN_F(i) float f##i = fmaf(qz##i, cp.z, fmaf(qy##i, cp.y, fmaf(qx##i, cp.x, cp.w)));
    KNN_FORQ(KNN_F)
#undef KNN_F
    bool hit = (f0 <= g0) | (f1 <= g1) | (f2 <= g2) | (f3 <= g3)
             | (f4 <= g4) | (f5 <= g5) | (f6 <= g6) | (f7 <= g7);
    if (hit) {                             // rare: skipped wholesale when no lane hits
#define KNN_PUSH(i) if (f##i <= g##i) { int s = atomicAdd(&sCnt[i], 1); if (s < CAP) sPos[i][s] = j; }
      KNN_FORQ(KNN_PUSH)
#undef KNN_PUSH
    }
  }
  __syncthreads();

  // ---- final: exact keys for survivors, u64 butterfly per (query, mode); wave wv owns
  // query wv x 2 modes = 2 butterflies/wave. Phase unchanged (verified).
  const ull KE = 0x7F800000FFFFFFFFull;
  const int qloc = wv;
  const float4 qv = Cb[s0 + qloc];          // exact coords, L2-hot re-read
  #pragma unroll
  for (int mode = 0; mode < 2; mode++) {
    int cnt = sCnt[qloc]; cnt = cnt > CAP ? CAP : cnt;
    ull k0 = KE, k1 = KE;
    if (lane < cnt) {
      int pos = sPos[qloc][lane];
      if (mode == 0 || pos < cS) {
        float4 cp = Cb[pos];
        float fe = fmaxf(d2exact_rn(qv.x, qv.y, qv.z, qv.w, cp.x, cp.y, cp.z, cp.w), 1e-12f);
        unsigned idx = mode ? (unsigned)pos : (unsigned)im[pos];
        k0 = ((ull)__float_as_uint(fe) << 32) | idx;
      }
    }
    if (lane + 64 < cnt) {
      int pos = sPos[qloc][lane + 64];
      if (mode == 0 || pos < cS) {
        float4 cp = Cb[pos];
        float fe = fmaxf(d2exact_rn(qv.x, qv.y, qv.z, qv.w, cp.x, cp.y, cp.z, cp.w), 1e-12f);
        unsigned idx = mode ? (unsigned)pos : (unsigned)im[pos];
        k1 = ((ull)__float_as_uint(fe) << 32) | idx;
      }
    }
    if (k1 < k0) { ull t = k0; k0 = k1; k1 = t; }
    ull k2 = KE, k3 = KE;
    #pragma unroll
    for (int off = 1; off < 64; off <<= 1) {
      ull b0 = __shfl_xor(k0, off, 64), b1 = __shfl_xor(k1, off, 64);
      ull b2 = __shfl_xor(k2, off, 64), b3 = __shfl_xor(k3, off, 64);
      ull m0 = k0 < b3 ? k0 : b3;
      ull m1 = k1 < b2 ? k1 : b2;
      ull m2 = k2 < b1 ? k2 : b1;
      ull m3 = k3 < b0 ? k3 : b0;
      ce64(m0, m2); ce64(m1, m3); ce64(m0, m1); ce64(m2, m3);
      k0 = m0; k1 = m1; k2 = m2; k3 = m3;
    }
    if (lane == 0) {
      int wq = qbase + qloc;
      int i0 = (int)(unsigned)k0, i1 = (int)(unsigned)k1;
      int i2 = (int)(unsigned)k2, i3 = (int)(unsigned)k3;
      float e1 = sqrtf(__uint_as_float((unsigned)(k1 >> 32)));
      float e2 = sqrtf(__uint_as_float((unsigned)(k2 >> 32)));
      float e3 = sqrtf(__uint_as_float((unsigned)(k3 >> 32)));
      float* tr = trans + wq * cTR + (mode ? 6 : 0);
      tr[0] = e1; tr[1] = e2; tr[2] = e3;
      int* ao = (mode ? AA : AB) + wq * 4;
      if (mode) { i0 = im[i0]; i1 = im[i1]; i2 = im[i2]; i3 = im[i3]; }
      ao[0] = i0; ao[1] = i1; ao[2] = i2; ao[3] = i3;
    }
  }
}

// ---- K3: anchor-anchor dists + 3-layer MLP. r8-VERIFIED 2-wave split-K (131.7 best).
// r9 lesson: 4-way split regressed (+4.8us — k-slices too thin, barriers/combine doubled).
// mlp latency curve mapped: 1/2/4/8 waves-SIMD -> ~21/~15/~12.5/regression. 2-way optimum.
__global__ __launch_bounds__(128, 4) void mlp_kernel(
    const float* __restrict__ TR, const float4* __restrict__ P,
    const int* __restrict__ AB, const int* __restrict__ AA,
    const float* __restrict__ feat, const int* __restrict__ smp,
    const float* __restrict__ w1, const float* __restrict__ b1,
    const float* __restrict__ g1, const float* __restrict__ be1,
    const float* __restrict__ w2, const float* __restrict__ b2,
    const float* __restrict__ g2, const float* __restrict__ be2,
    const float* __restrict__ w3, const float* __restrict__ b3,
    const float* __restrict__ g3, const float* __restrict__ be3,
    float* __restrict__ out) {
  __shared__ alignas(16) float tinT[28 * 4];
  __shared__ alignas(16) float act1T[64 * 4];
  __shared__ alignas(16) float act2T[128 * 4];   // ch 0..63 = feat, 64..127 = L2 out
  __shared__ alignas(16) float part[2][8][64];   // [wave][acc-slot][lane] partials

  const int tid = threadIdx.x;
  const int lane = tid & 63, w = tid >> 6;
  const int r0 = blockIdx.x * 4;
  const int b = r0 >> 12;
  const float inv = 1.0f / sqrtf(1.0f + 1e-5f);

  float pb1 = b1[lane], pg1 = g1[lane] * inv, pe1 = be1[lane];
  float pb2 = b2[lane], pg2 = g2[lane] * inv, pe2 = be2[lane];
  float pb3a = b3[lane],      pg3a = g3[lane] * inv,      pe3a = be3[lane];
  float pb3b = b3[lane + 64], pg3b = g3[lane + 64] * inv, pe3b = be3[lane + 64];

  // stage feat -> act2T ch 0..63: thread handles ch=lane, rows {2w, 2w+1}
  {
    const float* fb = feat + (size_t)b * cN * 64;
    float2 v;
    v.x = fb[smp[r0 + 2 * w + 0] * 64 + lane];
    v.y = fb[smp[r0 + 2 * w + 1] * 64 + lane];
    *(float2*)&act2T[lane * 4 + 2 * w] = v;
  }
  // stage tinT (28ch x 4r = 112 items): 128 threads, single pass
  {
    const float4* Pb = P + b * cN;
    int idx = tid;
    if (idx < 112) {
      int r = idx & 3, ch = idx >> 2;
      float v;
      if (ch < 3) {
        v = TR[(r0 + r) * cTR + ch];
      } else if (ch < 6) {
        int pi = (ch == 3) ? 1 : 1 + (ch - 4), pj = (ch == 3) ? 2 : 3;
        if (ch == 5) { pi = 2; pj = 3; }
        v = dist_rn4(Pb[AB[(r0 + r) * 4 + pi]], Pb[AB[(r0 + r) * 4 + pj]]);
      } else if (ch < 9) {
        v = TR[(r0 + r) * cTR + ch];
      } else if (ch < 12) {
        int cc = ch - 9;
        int pi = (cc == 0) ? 1 : ((cc == 1) ? 1 : 2);
        int pj = (cc == 0) ? 2 : 3;
        v = dist_rn4(Pb[AA[(r0 + r) * 4 + pi]], Pb[AA[(r0 + r) * 4 + pj]]);
      } else {
        int cc = ch - 12;
        int gi = AB[(r0 + r) * 4 + (cc >> 2)];
        int gj = AA[(r0 + r) * 4 + (cc & 3)];
        v = dist_rn4(Pb[gi], Pb[gj]);
      }
      tinT[ch * 4 + r] = v;
    }
  }
  __syncthreads();

  // L1: 28 -> 64, k-split [14w, 14w+14)
  {
    float4 acc = (w == 0) ? make_float4(pb1, pb1, pb1, pb1)
                          : make_float4(0.f, 0.f, 0.f, 0.f);
    #pragma unroll 7
    for (int k = 14 * w; k < 14 * w + 14; k++) {
      float ww = w1[k * 64 + lane];
      float4 a = *(const float4*)&tinT[k * 4];
      acc.x = fmaf(a.x, ww, acc.x); acc.y = fmaf(a.y, ww, acc.y);
      acc.z = fmaf(a.z, ww, acc.z); acc.w = fmaf(a.w, ww, acc.w);
    }
    part[w][0][lane] = acc.x; part[w][1][lane] = acc.y;
    part[w][2][lane] = acc.z; part[w][3][lane] = acc.w;
    __syncthreads();
    // combine: wave w handles rows 2w, 2w+1
    int rA = 2 * w, rB = 2 * w + 1;
    float oA = part[0][rA][lane] + part[1][rA][lane];
    float oB = part[0][rB][lane] + part[1][rB][lane];
    oA = fmaf(oA, pg1, pe1); oB = fmaf(oB, pg1, pe1);
    oA = oA >= 0.0f ? oA : 0.2f * oA; oB = oB >= 0.0f ? oB : 0.2f * oB;
    __syncthreads();                      // part reuse guard
    act1T[lane * 4 + rA] = oA;
    act1T[lane * 4 + rB] = oB;
  }
  __syncthreads();
  // L2: 64 -> 64, k-split [32w, 32w+32)
  {
    float4 acc = (w == 0) ? make_float4(pb2, pb2, pb2, pb2)
                          : make_float4(0.f, 0.f, 0.f, 0.f);
    #pragma unroll 8
    for (int k = 32 * w; k < 32 * w + 32; k++) {
      float ww = w2[k * 64 + lane];
      float4 a = *(const float4*)&act1T[k * 4];
      acc.x = fmaf(a.x, ww, acc.x); acc.y = fmaf(a.y, ww, acc.y);
      acc.z = fmaf(a.z, ww, acc.z); acc.w = fmaf(a.w, ww, acc.w);
    }
    part[w][0][lane] = acc.x; part[w][1][lane] = acc.y;
    part[w][2][lane] = acc.z; part[w][3][lane] = acc.w;
    __syncthreads();
    int rA = 2 * w, rB = 2 * w + 1;
    float oA = part[0][rA][lane] + part[1][rA][lane];
    float oB = part[0][rB][lane] + part[1][rB][lane];
    oA = fmaf(oA, pg2, pe2); oB = fmaf(oB, pg2, pe2);
    oA = oA >= 0.0f ? oA : 0.2f * oA; oB = oB >= 0.0f ? oB : 0.2f * oB;
    __syncthreads();                      // part reuse guard
    act2T[(64 + lane) * 4 + rA] = oA;
    act2T[(64 + lane) * 4 + rB] = oB;
  }
  __syncthreads();
  // L3: 128 -> 128 (lane covers ch and ch+64), k-split [64w, 64w+64)
  {
    float4 aA = (w == 0) ? make_float4(pb3a, pb3a, pb3a, pb3a)
                         : make_float4(0.f, 0.f, 0.f, 0.f);
    float4 aB = (w == 0) ? make_float4(pb3b, pb3b, pb3b, pb3b)
                         : make_float4(0.f, 0.f, 0.f, 0.f);
    #pragma unroll 8
    for (int k = 64 * w; k < 64 * w + 64; k++) {
      float wA = w3[k * 128 + lane];
      float wB = w3[k * 128 + 64 + lane];
      float4 a = *(const float4*)&act2T[k * 4];
      aA.x = fmaf(a.x, wA, aA.x); aA.y = fmaf(a.y, wA, aA.y);
      aA.z = fmaf(a.z, wA, aA.z); aA.w = fmaf(a.w, wA, aA.w);
      aB.x = fmaf(a.x, wB, aB.x); aB.y = fmaf(a.y, wB, aB.y);
      aB.z = fmaf(a.z, wB, aB.z); aB.w = fmaf(a.w, wB, aB.w);
    }
    part[w][0][lane] = aA.x; part[w][1][lane] = aA.y;
    part[w][2][lane] = aA.z; part[w][3][lane] = aA.w;
    part[w][4][lane] = aB.x; part[w][5][lane] = aB.y;
    part[w][6][lane] = aB.z; part[w][7][lane] = aB.w;
    __syncthreads();
    // combine + store: wave w handles rows 2w, 2w+1 for both channel halves
    int rA = 2 * w, rB = 2 * w + 1;
    float sA0 = part[0][rA][lane]     + part[1][rA][lane];
    float sA1 = part[0][rB][lane]     + part[1][rB][lane];
    float sB0 = part[0][4 + rA][lane] + part[1][4 + rA][lane];
    float sB1 = part[0][4 + rB][lane] + part[1][4 + rB][lane];
    float xA, xB;
    xA = fmaf(sA0, pg3a, pe3a); xB = fmaf(sB0, pg3b, pe3b);
    xA = xA >= 0.0f ? xA : 0.2f * xA; xB = xB >= 0.0f ? xB : 0.2f * xB;
    out[(r0 + rA) * 128 + lane] = xA; out[(r0 + rA) * 128 + 64 + lane] = xB;
    xA = fmaf(sA1, pg3a, pe3a); xB = fmaf(sB1, pg3b, pe3b);
    xA = xA >= 0.0f ? xA : 0.2f * xA; xB = xB >= 0.0f ? xB : 0.2f * xB;
    out[(r0 + rB) * 128 + lane] = xA; out[(r0 + rB) * 128 + 64 + lane] = xB;
  }
}

extern "C" void kernel_launch(void* const* d_in, const int* in_sizes, int n_in,
                              void* d_out, int out_size, void* d_ws, size_t ws_size,
                              hipStream_t stream) {
  const float* xyz  = (const float*)d_in[0];
  const float* feat = (const float*)d_in[1];
  const int*   smp  = (const int*)d_in[2];
  const float* w1   = (const float*)d_in[3];
  const float* b1   = (const float*)d_in[4];
  const float* g1   = (const float*)d_in[5];
  const float* be1  = (const float*)d_in[6];
  const float* w2   = (const float*)d_in[7];
  const float* b2   = (const float*)d_in[8];
  const float* g2   = (const float*)d_in[9];
  const float* be2  = (const float*)d_in[10];
  const float* w3   = (const float*)d_in[11];
  const float* b3   = (const float*)d_in[12];
  const float* g3   = (const float*)d_in[13];
  const float* be3  = (const float*)d_in[14];
  float* out = (float*)d_out;

  char* ws = (char*)d_ws;
  float4* P      = (float4*)(ws);                 // 262144 B
  float4* P2     = (float4*)(ws + 262144);        // 262144 B
  int*    idxMap = (int*)(ws + 524288);           // 65536 B
  float*  TR     = (float*)(ws + 589824);         // B*S*12*4 = 393216 B
  int*    AB     = (int*)(ws + 983040);           // 131072 B
  int*    AA     = (int*)(ws + 1114112);          // 131072 B

  pack_kernel<<<48, 512, 0, stream>>>(xyz, smp, P, P2, idxMap, out);
  knn_kernel<<<cB * cS / QPB, TPB, 0, stream>>>(P2, idxMap, TR, AB, AA);
  mlp_kernel<<<2048, 128, 0, stream>>>(TR, P, AB, AA, feat, smp,
                                       w1, b1, g1, be1, w2, b2, g2, be2,
                                       w3, b3, g3, be3, out + cB * cS * 3);
}